// Round 16
// baseline (8939.055 us; speedup 1.0000x reference)
//
#include <hip/hip_runtime.h>

typedef unsigned short u16;
typedef unsigned int   u32;
typedef unsigned long long u64;
typedef short s16x4 __attribute__((ext_vector_type(4)));
typedef short s16x8 __attribute__((ext_vector_type(8)));
typedef float f32x4 __attribute__((ext_vector_type(4)));
typedef u32   u32x4 __attribute__((ext_vector_type(4)));

#define GK 1024

__device__ inline u16 f2bf(float f) {
    u32 u = __builtin_bit_cast(u32, f);
    u += 0x7FFFu + ((u >> 16) & 1u);
    return (u16)(u >> 16);
}
__device__ inline u16 f2h(float f) {
    _Float16 h = (_Float16)f;
    return __builtin_bit_cast(u16, h);
}
__device__ inline float h2f(u16 u) {
    return (float)__builtin_bit_cast(_Float16, u);
}
__device__ inline float fast_sigmoid(float x) {
    return __builtin_amdgcn_rcpf(1.f + __expf(-x));
}
__device__ inline float fast_tanh(float x) {
    return 1.f - 2.f * __builtin_amdgcn_rcpf(1.f + __expf(2.f * x));
}
__device__ inline f32x4 mfma16(s16x8 a, s16x8 b, f32x4 c) {
    return __builtin_amdgcn_mfma_f32_16x16x32_bf16(a, b, c, 0, 0, 0);
}
__device__ inline s16x8 mk8(s16x4 lo, s16x4 hi) {
    return __builtin_shufflevector(lo, hi, 0, 1, 2, 3, 4, 5, 6, 7);
}

// ---------------- transpose + convert: out[c][r] = bf16(in[r][c]) ----------------
__global__ void k_transpose_bf(const float* __restrict__ in, u16* __restrict__ out,
                               int R, int C) {
    __shared__ float tile[32][33];
    int tid = threadIdx.x;
    int xs = (tid & 7) * 4;
    int y  = tid >> 3;
    int r0 = blockIdx.y * 32, c0 = blockIdx.x * 32;
    float4 v = *(const float4*)(in + (size_t)(r0 + y) * C + c0 + xs);
    tile[y][xs + 0] = v.x; tile[y][xs + 1] = v.y;
    tile[y][xs + 2] = v.z; tile[y][xs + 3] = v.w;
    __syncthreads();
    ushort4 o;
    o.x = f2bf(tile[xs + 0][y]); o.y = f2bf(tile[xs + 1][y]);
    o.z = f2bf(tile[xs + 2][y]); o.w = f2bf(tile[xs + 3][y]);
    *(ushort4*)(out + (size_t)(c0 + y) * R + r0 + xs) = o;
}

// ---------------- in-place frag-pack of a [cols][1024] bf16 matrix (r12-proven) ------
__global__ void k_wpackip(u16* __restrict__ wm) {
    int idx = blockIdx.x * 256 + threadIdx.x;
    u64* p = (u64*)(wm + (size_t)idx * 32);
    u64 w0 = p[0], w1 = p[1], w2 = p[2], w3 = p[3];
    u64 w4 = p[4], w5 = p[5], w6 = p[6], w7 = p[7];
    p[0] = w0; p[1] = w4; p[2] = w1; p[3] = w5;
    p[4] = w2; p[5] = w6; p[6] = w3; p[7] = w7;
}

// ---------------- unpack permuted hseq1 -> plain [t*32+b][1024] (r12-proven) ----------
__global__ void k_unpack(const u16* __restrict__ in, u16* __restrict__ out) {
    int idx = blockIdx.x * 256 + threadIdx.x;
    int slot = idx >> 12;
    int c = idx & 4095;
    int q = c >> 7, b = (c >> 2) & 31, ri = c & 3;
    const u16* p = in + (size_t)(slot + 1) * 32768 + q * 1024 + b * 32 + ri * 8;
    u64 lo = *(const u64*)p;
    u64 hi = *(const u64*)(p + 4);
    u16* o = out + (size_t)(slot * 32 + b) * 1024 + q * 32 + ri * 4;
    *(u64*)o = lo;
    *(u64*)(o + 16) = hi;
}

// ---------------- bf16 GEMM ----------------
// MODE 0: A read from f32 (Af) with in-staging bf16 conversion; xproj epilogue:
//         orow=(m&511)*32+(m>>9), fp16 gate-interleaved.
// MODE 1: A u16 plain [M][1024]; heads: orow=(m&31)*512+(m>>5);
//         n<256 softplus+ymin -> mu; n>=256 -> log_sigma.
template<int MODE>
__launch_bounds__(256, 2)
__global__ void k_gemm(const u16* __restrict__ A, const float* __restrict__ Af,
                       const u16* __restrict__ BT,
                       const float* __restrict__ bias,
                       u16* __restrict__ Cb, float* __restrict__ Cf,
                       const float* __restrict__ b2, const float* __restrict__ ymin,
                       int gridN) {
    int bid = blockIdx.x;
    int m0 = (bid / gridN) * 128, n0 = (bid % gridN) * 128;
    __shared__ u16 As[128 * 40];
    __shared__ u16 Bs[128 * 40];
    int tid = threadIdx.x;
    int lane = tid & 63, w = tid >> 6;
    int wr = w >> 1, wc = w & 1;
    int rr = lane & 15, r16 = lane >> 4;
    f32x4 acc[4][4] = {};
    for (int kt = 0; kt < GK / 32; ++kt) {
        int k0 = kt * 32;
#pragma unroll
        for (int it = 0; it < 2; ++it) {
            int idx = it * 256 + tid;
            int row = idx >> 2, ch = idx & 3;
            if (MODE == 0) {
                const float* ap = Af + (size_t)(m0 + row) * GK + k0 + ch * 8;
                float4 vlo = *(const float4*)ap;
                float4 vhi = *(const float4*)(ap + 4);
                u16* d = &As[row * 40 + ch * 8];
                d[0] = f2bf(vlo.x); d[1] = f2bf(vlo.y);
                d[2] = f2bf(vlo.z); d[3] = f2bf(vlo.w);
                d[4] = f2bf(vhi.x); d[5] = f2bf(vhi.y);
                d[6] = f2bf(vhi.z); d[7] = f2bf(vhi.w);
            } else {
                *(u32x4*)(&As[row * 40 + ch * 8]) =
                    *(const u32x4*)(A + (size_t)(m0 + row) * GK + k0 + ch * 8);
            }
            *(u32x4*)(&Bs[row * 40 + ch * 8]) =
                *(const u32x4*)(BT + (size_t)(n0 + row) * GK + k0 + ch * 8);
        }
        __syncthreads();
        s16x8 af[4], bfr[4];
#pragma unroll
        for (int i = 0; i < 4; ++i) {
            int abase = (wr * 64 + i * 16 + rr) * 40 + r16 * 4;
            af[i] = mk8(*(const s16x4*)(&As[abase]), *(const s16x4*)(&As[abase + 16]));
            int bbase = (wc * 64 + i * 16 + rr) * 40 + r16 * 4;
            bfr[i] = mk8(*(const s16x4*)(&Bs[bbase]), *(const s16x4*)(&Bs[bbase + 16]));
        }
#pragma unroll
        for (int i = 0; i < 4; ++i)
#pragma unroll
            for (int j = 0; j < 4; ++j)
                acc[i][j] = mfma16(af[i], bfr[j], acc[i][j]);
        __syncthreads();
    }
#pragma unroll
    for (int i = 0; i < 4; ++i) {
#pragma unroll
        for (int j = 0; j < 4; ++j) {
#pragma unroll
            for (int r = 0; r < 4; ++r) {
                int m = m0 + wr * 64 + i * 16 + r16 * 4 + r;
                int n = n0 + wc * 64 + j * 16 + rr;
                float v = acc[i][j][r];
                if (MODE == 0) {
                    v += bias[n];
                    int orow = (m & 511) * 32 + (m >> 9);
                    int colx = ((n & 1023) << 2) | (n >> 10);
                    Cb[(size_t)orow * 4096 + colx] = f2h(v);
                } else {
                    int orow = (m & 31) * 512 + (m >> 5);
                    if (n < 256) {
                        v += bias[n];
                        float sp = fmaxf(v, 0.f) + log1pf(expf(-fabsf(v)));
                        Cf[(size_t)orow * 256 + n] = sp + ymin[n];
                    } else {
                        v += b2[n - 256];
                        Cf[4194304 + (size_t)orow * 256 + (n - 256)] = v;
                    }
                }
            }
        }
    }
}

// ---------------- LSTM helpers (r11/r12/r15-proven) ----------------
__device__ inline float lstm_core(f32x4 acc, float ai, float af, float ag, float ao,
                                  float& c, int lane) {
    float r0 = acc[0], r1 = acc[1], r2 = acc[2], r3 = acc[3];
    float x0 = __shfl_xor(r0, 1), x1 = __shfl_xor(r1, 1);
    float x2 = __shfl_xor(r2, 1), x3 = __shfl_xor(r3, 1);
    bool o1 = lane & 1;
    float s0 = o1 ? x1 : r0, s1 = o1 ? r1 : x0;
    float s2 = o1 ? x3 : r2, s3 = o1 ? r3 : x2;
    float y0 = __shfl_xor(s0, 2), y1 = __shfl_xor(s1, 2);
    float y2 = __shfl_xor(s2, 2), y3 = __shfl_xor(s3, 2);
    bool o2 = lane & 2;
    float gi = (o2 ? y2 : s0) + ai;
    float gf = (o2 ? y3 : s1) + af;
    float gg = (o2 ? s2 : y0) + ag;
    float go = (o2 ? s3 : y1) + ao;
    float I  = fast_sigmoid(gi);
    float Fg = fast_sigmoid(gf);
    float G  = fast_tanh(gg);
    float O  = fast_sigmoid(go);
    c = Fg * c + I * G;
    return O * fast_tanh(c);
}
__device__ inline void pack_plain(float h, int lane, u16* dst) {
    u32 hq = (u32)f2bf(h);
    u32 o4 = (u32)__shfl_xor((int)hq, 4);
    u32 m32 = (lane & 4) ? ((o4 & 0xffffu) | (hq << 16))
                         : ((hq & 0xffffu) | (o4 << 16));
    u32 o8 = (u32)__shfl_xor((int)m32, 8);
    u64 m64 = (lane & 8) ? (((u64)o8) | ((u64)m32 << 32))
                         : (((u64)m32) | ((u64)o8 << 32));
    if ((lane & 12) == 0) *(u64*)dst = m64;
}
__device__ inline int e0_of(int base) {
    return ((base & 15) >> 2) * 8 + ((base >> 4) & 1) * 4;
}

// ---------------- per-timestep kernel: boundary IS the sync (r15-proven, merged) ------
// 128 blocks x 512 threads (8 waves, 2/SIMD). Block owns units [blk*8,+8) of BOTH layers.
// Waves 0-3 (mt=wl&1, qh=wl>>1): L0 step t (hbuf0 slot t&1 -> (t+1)&1), inert at t=512.
// Waves 4-7: L1 step t (h1[t-1] + h0[t]*Wx1 -> hseq1 slot t), inert at t=0.
// All loads/stores PLAIN (dependent-dispatch coherence). Weights frag-packed.
// One block-wide barrier between compute and epilogue (uniform; no early returns).
__launch_bounds__(512, 2)
__global__ void k_step(int t,
                       const u16* __restrict__ Wp0, const u16* __restrict__ Wpx,
                       const u16* __restrict__ Wp1, const u16* __restrict__ xproj,
                       const float* __restrict__ b1,
                       u16* __restrict__ hbuf0, u16* __restrict__ hseq1,
                       float* __restrict__ c0buf, float* __restrict__ c1buf) {
    __shared__ f32x4 part0[2][2][64];      // [mt][ct][lane]           (L0)
    __shared__ f32x4 part1[2][2][2][64];   // [mt][ct][src H/X][lane]  (L1)
    int tid = threadIdx.x, blk = blockIdx.x;
    int lane = tid & 63, w = tid >> 6;
    int isL1 = w >> 2, wl = w & 3;
    int mt = wl & 1, qh = wl >> 1;
    int rr = lane & 15, r16 = lane >> 4;
    int b_ = mt * 16 + ((lane >> 4) << 2) + (lane & 3);
    int uu = (lane >> 2) & 3;
    const int cb = mt * 512 + rr * 32 + r16 * 8;
    size_t cg0 = (size_t)((rr & 3) * 1024 + blk * 8 + (rr >> 2));
    size_t woff = qh * 512 + r16 * 8;

    f32x4 v0 = {}, v1 = {}, v2 = {}, v3 = {};
    if (!isL1) {
        if (t < 512) {
            const u16* w0 = Wp0 + cg0 * GK + woff;
            const u16* w1 = Wp0 + (cg0 + 4) * GK + woff;
            const u16* hp = hbuf0 + (size_t)(t & 1) * 32768 + qh * 16384 + cb;
            u32x4 hf[16];
#pragma unroll
            for (int j = 0; j < 16; ++j) hf[j] = *(const u32x4*)(hp + j * 1024);
#pragma unroll
            for (int j = 0; j < 16; ++j) {
                s16x8 a = __builtin_bit_cast(s16x8, hf[j]);
                v0 = mfma16(a, *(const s16x8*)(w0 + j * 32), v0);
                v1 = mfma16(a, *(const s16x8*)(w1 + j * 32), v1);
            }
            part0[mt][1 - qh][lane] = qh ? v0 : v1;
        }
    } else {
        if (t >= 1) {
            const u16* wh0 = Wp1 + cg0 * GK + woff;
            const u16* wh1 = Wp1 + (cg0 + 4) * GK + woff;
            const u16* wx0 = Wpx + cg0 * GK + woff;
            const u16* wx1 = Wpx + (cg0 + 4) * GK + woff;
            const u16* hp1 = hseq1 + (size_t)(t - 1) * 32768 + qh * 16384 + cb;
            const u16* hp0 = hbuf0 + (size_t)(t & 1) * 32768 + qh * 16384 + cb;
            u32x4 hf[16], gfr[16];
#pragma unroll
            for (int j = 0; j < 16; ++j) hf[j] = *(const u32x4*)(hp1 + j * 1024);
#pragma unroll
            for (int j = 0; j < 16; ++j) gfr[j] = *(const u32x4*)(hp0 + j * 1024);
#pragma unroll
            for (int j = 0; j < 16; ++j) {
                s16x8 a = __builtin_bit_cast(s16x8, hf[j]);
                v0 = mfma16(a, *(const s16x8*)(wh0 + j * 32), v0);
                v1 = mfma16(a, *(const s16x8*)(wh1 + j * 32), v1);
                s16x8 g = __builtin_bit_cast(s16x8, gfr[j]);
                v2 = mfma16(g, *(const s16x8*)(wx0 + j * 32), v2);
                v3 = mfma16(g, *(const s16x8*)(wx1 + j * 32), v3);
            }
            part1[mt][1 - qh][0][lane] = qh ? v0 : v1;
            part1[mt][1 - qh][1][lane] = qh ? v2 : v3;
        }
    }
    __syncthreads();

    if (!isL1) {
        if (t < 512) {
            f32x4 acc = (qh ? v1 : v0) + part0[mt][qh][lane];
            int unit = blk * 8 + qh * 4 + uu;
            u64 xv = *(const u64*)(xproj + (size_t)(t * 32 + b_) * 4096 + unit * 4);
            float c = c0buf[b_ * 1024 + unit];
            float h = lstm_core(acc, h2f((u16)xv), h2f((u16)(xv >> 16)),
                                h2f((u16)(xv >> 32)), h2f((u16)(xv >> 48)), c, lane);
            c0buf[b_ * 1024 + unit] = c;
            int E0 = e0_of((blk & 3) * 8 + qh * 4);
            u16* dst = hbuf0 + (size_t)((t + 1) & 1) * 32768 + (blk >> 2) * 1024
                     + b_ * 32 + E0;
            pack_plain(h, lane, dst);
        }
    } else {
        if (t >= 1) {
            f32x4 acc = (qh ? v1 : v0) + (qh ? v3 : v2)
                      + part1[mt][qh][0][lane] + part1[mt][qh][1][lane];
            int unit = blk * 8 + qh * 4 + uu;
            float c = c1buf[b_ * 1024 + unit];
            float h = lstm_core(acc, b1[unit], b1[1024 + unit], b1[2048 + unit],
                                b1[3072 + unit], c, lane);
            c1buf[b_ * 1024 + unit] = c;
            int E0 = e0_of((blk & 3) * 8 + qh * 4);
            u16* dst = hseq1 + (size_t)t * 32768 + (blk >> 2) * 1024 + b_ * 32 + E0;
            pack_plain(h, lane, dst);
        }
    }
}

extern "C" void kernel_launch(void* const* d_in, const int* in_sizes, int n_in,
                              void* d_out, int out_size, void* d_ws, size_t ws_size,
                              hipStream_t stream) {
    const float* x   = (const float*)d_in[0];
    const float* Wx  = (const float*)d_in[1];
    const float* Wh  = (const float*)d_in[2];
    const float* b   = (const float*)d_in[3];
    const float* Wmu = (const float*)d_in[4];
    const float* bmu = (const float*)d_in[5];
    const float* Wls = (const float*)d_in[6];
    const float* bls = (const float*)d_in[7];
    const float* ym  = (const float*)d_in[8];
    float* out = (float*)d_out;

    // workspace (235,995,136 B total; no aliasing of live buffers):
    // [0)            hbuf0[2][32768] u16 (131,072) ; c0 (131,072) ; c1 (131,072)
    // [33,554,432)   wxT   16,777,216   [2][4096][1024] (layer1 half frag-packed)
    // [50,331,648)   whT   16,777,216   (frag-packed in place)
    // [67,108,864)   whdT   1,048,576
    // [68,157,440)   xproj 134,217,728  fp16 gate-interleaved (h1lin alias after steps)
    // [202,375,168)  hseq1 33,619,968   [513][32768]
    char* ws = (char*)d_ws;
    u16*   hbuf0 = (u16*)(ws);
    float* c0buf = (float*)(ws + 131072);
    float* c1buf = (float*)(ws + 262144);
    u16*   wxT   = (u16*)(ws + 33554432);
    u16*   whT   = (u16*)(ws + 50331648);
    u16*   whdT  = (u16*)(ws + 67108864);
    u16*   xproj = (u16*)(ws + 68157440);
    u16*   h1lin = xproj;                        // xproj dead after steps
    u16*   hseq1 = (u16*)(ws + 202375168);

    // prep: weight transposes
    dim3 tg(128, 32);
    k_transpose_bf<<<tg, 256, 0, stream>>>(Wx,           wxT,           1024, 4096);
    k_transpose_bf<<<tg, 256, 0, stream>>>(Wx + 4194304, wxT + 4194304, 1024, 4096);
    k_transpose_bf<<<tg, 256, 0, stream>>>(Wh,           whT,           1024, 4096);
    k_transpose_bf<<<tg, 256, 0, stream>>>(Wh + 4194304, whT + 4194304, 1024, 4096);
    dim3 hg(8, 32);
    k_transpose_bf<<<hg, 256, 0, stream>>>(Wmu, whdT,          1024, 256);
    k_transpose_bf<<<hg, 256, 0, stream>>>(Wls, whdT + 262144, 1024, 256);

    // layer-0 x-projection straight from f32 x (in-staging bf16 conversion)
    k_gemm<0><<<4096, 256, 0, stream>>>(nullptr, x, wxT, b, xproj,
                                        nullptr, nullptr, nullptr, 32);

    // frag-pack recurrence weights in place (whT both layers, wxT layer 1)
    k_wpackip<<<1024, 256, 0, stream>>>(whT);
    k_wpackip<<<512, 256, 0, stream>>>(wxT + 4194304);

    // init state: h0 slot0, c0, c1, h1 slot0 = 0
    hipMemsetAsync(hbuf0, 0, 65536, stream);
    hipMemsetAsync(c0buf, 0, 262144, stream);
    hipMemsetAsync(hseq1, 0, 65536, stream);

    // 513 per-step kernels; dependent-dispatch boundary = global sync
    for (int t = 0; t <= 512; ++t)
        k_step<<<128, 512, 0, stream>>>(t, whT, wxT + 4194304, whT + 4194304, xproj,
                                        b + 4096, hbuf0, hseq1, c0buf, c1buf);

    // unpack hseq1 -> plain rows, then heads
    k_unpack<<<8192, 256, 0, stream>>>(hseq1, h1lin);
    k_gemm<1><<<512, 256, 0, stream>>>(h1lin, nullptr, whdT, bmu, nullptr, out,
                                       bls, ym, 4);
}

// Round 17
// 6676.868 us; speedup vs baseline: 1.3388x; 1.3388x over previous
//
#include <hip/hip_runtime.h>

typedef unsigned short u16;
typedef unsigned int   u32;
typedef unsigned long long u64;
typedef short s16x4 __attribute__((ext_vector_type(4)));
typedef short s16x8 __attribute__((ext_vector_type(8)));
typedef float f32x4 __attribute__((ext_vector_type(4)));
typedef u32   u32x4 __attribute__((ext_vector_type(4)));

#define GK 1024

__device__ inline u16 f2bf(float f) {
    u32 u = __builtin_bit_cast(u32, f);
    u += 0x7FFFu + ((u >> 16) & 1u);
    return (u16)(u >> 16);
}
__device__ inline u16 f2h(float f) {
    _Float16 h = (_Float16)f;
    return __builtin_bit_cast(u16, h);
}
__device__ inline float h2f(u16 u) {
    return (float)__builtin_bit_cast(_Float16, u);
}
__device__ inline float fast_sigmoid(float x) {
    return __builtin_amdgcn_rcpf(1.f + __expf(-x));
}
__device__ inline float fast_tanh(float x) {
    return 1.f - 2.f * __builtin_amdgcn_rcpf(1.f + __expf(2.f * x));
}
__device__ inline f32x4 mfma16(s16x8 a, s16x8 b, f32x4 c) {
    return __builtin_amdgcn_mfma_f32_16x16x32_bf16(a, b, c, 0, 0, 0);
}
__device__ inline s16x8 mk8(s16x4 lo, s16x4 hi) {
    return __builtin_shufflevector(lo, hi, 0, 1, 2, 3, 4, 5, 6, 7);
}

// ---------------- f32 -> bf16 convert (x) ----------------
__global__ void k_f2bf(const float* __restrict__ in, u16* __restrict__ out, int n) {
    int i = (blockIdx.x * 256 + threadIdx.x) * 4;
    if (i < n) {
        float4 v = *(const float4*)(in + i);
        ushort4 o;
        o.x = f2bf(v.x); o.y = f2bf(v.y); o.z = f2bf(v.z); o.w = f2bf(v.w);
        *(ushort4*)(out + i) = o;
    }
}

// ---------------- transpose + convert: out[c][r] = bf16(in[r][c]) ----------------
__global__ void k_transpose_bf(const float* __restrict__ in, u16* __restrict__ out,
                               int R, int C) {
    __shared__ float tile[32][33];
    int tid = threadIdx.x;
    int xs = (tid & 7) * 4;
    int y  = tid >> 3;
    int r0 = blockIdx.y * 32, c0 = blockIdx.x * 32;
    float4 v = *(const float4*)(in + (size_t)(r0 + y) * C + c0 + xs);
    tile[y][xs + 0] = v.x; tile[y][xs + 1] = v.y;
    tile[y][xs + 2] = v.z; tile[y][xs + 3] = v.w;
    __syncthreads();
    ushort4 o;
    o.x = f2bf(tile[xs + 0][y]); o.y = f2bf(tile[xs + 1][y]);
    o.z = f2bf(tile[xs + 2][y]); o.w = f2bf(tile[xs + 3][y]);
    *(ushort4*)(out + (size_t)(c0 + y) * R + r0 + xs) = o;
}

// ---------------- in-place frag-pack of a [cols][1024] bf16 matrix (r12-proven) ------
// Per 64B chunk (32 elems): out u64 words = [w0,w4,w1,w5,w2,w6,w3,w7] so a dwordx4 at
// +r16*8 elems is the MFMA B-frag (k = r16*4 + (j&3) + 16*(j>>2)).
__global__ void k_wpackip(u16* __restrict__ wm) {
    int idx = blockIdx.x * 256 + threadIdx.x;
    u64* p = (u64*)(wm + (size_t)idx * 32);
    u64 w0 = p[0], w1 = p[1], w2 = p[2], w3 = p[3];
    u64 w4 = p[4], w5 = p[5], w6 = p[6], w7 = p[7];
    p[0] = w0; p[1] = w4; p[2] = w1; p[3] = w5;
    p[4] = w2; p[5] = w6; p[6] = w3; p[7] = w7;
}

// ---------------- unpack permuted hseq1 -> plain [t*32+b][1024] (r12-proven) ----------
__global__ void k_unpack(const u16* __restrict__ in, u16* __restrict__ out) {
    int idx = blockIdx.x * 256 + threadIdx.x;
    int slot = idx >> 12;
    int c = idx & 4095;
    int q = c >> 7, b = (c >> 2) & 31, ri = c & 3;
    const u16* p = in + (size_t)(slot + 1) * 32768 + q * 1024 + b * 32 + ri * 8;
    u64 lo = *(const u64*)p;
    u64 hi = *(const u64*)(p + 4);
    u16* o = out + (size_t)(slot * 32 + b) * 1024 + q * 32 + ri * 4;
    *(u64*)o = lo;
    *(u64*)(o + 16) = hi;
}

// ---------------- bf16 GEMM (A plain [M][1024]) ----------------
// MODE 0: xproj: orow=(m&511)*32+(m>>9), fp16 gate-interleaved.
// MODE 1: heads: orow=(m&31)*512+(m>>5); n<256 softplus+ymin -> mu; n>=256 -> log_sigma.
template<int MODE>
__launch_bounds__(256, 2)
__global__ void k_gemm(const u16* __restrict__ A, const u16* __restrict__ BT,
                       const float* __restrict__ bias,
                       u16* __restrict__ Cb, float* __restrict__ Cf,
                       const float* __restrict__ b2, const float* __restrict__ ymin,
                       int gridN) {
    int bid = blockIdx.x;
    int m0 = (bid / gridN) * 128, n0 = (bid % gridN) * 128;
    __shared__ u16 As[128 * 40];
    __shared__ u16 Bs[128 * 40];
    int tid = threadIdx.x;
    int lane = tid & 63, w = tid >> 6;
    int wr = w >> 1, wc = w & 1;
    int rr = lane & 15, r16 = lane >> 4;
    f32x4 acc[4][4] = {};
    for (int kt = 0; kt < GK / 32; ++kt) {
        int k0 = kt * 32;
#pragma unroll
        for (int it = 0; it < 2; ++it) {
            int idx = it * 256 + tid;
            int row = idx >> 2, ch = idx & 3;
            *(u32x4*)(&As[row * 40 + ch * 8]) =
                *(const u32x4*)(A + (size_t)(m0 + row) * GK + k0 + ch * 8);
            *(u32x4*)(&Bs[row * 40 + ch * 8]) =
                *(const u32x4*)(BT + (size_t)(n0 + row) * GK + k0 + ch * 8);
        }
        __syncthreads();
        s16x8 af[4], bfr[4];
#pragma unroll
        for (int i = 0; i < 4; ++i) {
            int abase = (wr * 64 + i * 16 + rr) * 40 + r16 * 4;
            af[i] = mk8(*(const s16x4*)(&As[abase]), *(const s16x4*)(&As[abase + 16]));
            int bbase = (wc * 64 + i * 16 + rr) * 40 + r16 * 4;
            bfr[i] = mk8(*(const s16x4*)(&Bs[bbase]), *(const s16x4*)(&Bs[bbase + 16]));
        }
#pragma unroll
        for (int i = 0; i < 4; ++i)
#pragma unroll
            for (int j = 0; j < 4; ++j)
                acc[i][j] = mfma16(af[i], bfr[j], acc[i][j]);
        __syncthreads();
    }
#pragma unroll
    for (int i = 0; i < 4; ++i) {
#pragma unroll
        for (int j = 0; j < 4; ++j) {
#pragma unroll
            for (int r = 0; r < 4; ++r) {
                int m = m0 + wr * 64 + i * 16 + r16 * 4 + r;
                int n = n0 + wc * 64 + j * 16 + rr;
                float v = acc[i][j][r];
                if (MODE == 0) {
                    v += bias[n];
                    int orow = (m & 511) * 32 + (m >> 9);
                    int colx = ((n & 1023) << 2) | (n >> 10);
                    Cb[(size_t)orow * 4096 + colx] = f2h(v);
                } else {
                    int orow = (m & 31) * 512 + (m >> 5);
                    if (n < 256) {
                        v += bias[n];
                        float sp = fmaxf(v, 0.f) + log1pf(expf(-fabsf(v)));
                        Cf[(size_t)orow * 256 + n] = sp + ymin[n];
                    } else {
                        v += b2[n - 256];
                        Cf[4194304 + (size_t)orow * 256 + (n - 256)] = v;
                    }
                }
            }
        }
    }
}

// ---------------- LSTM helpers (r11/r12/r14-proven) ----------------
__device__ inline float lstm_core(f32x4 acc, float ai, float af, float ag, float ao,
                                  float& c, int lane) {
    float r0 = acc[0], r1 = acc[1], r2 = acc[2], r3 = acc[3];
    float x0 = __shfl_xor(r0, 1), x1 = __shfl_xor(r1, 1);
    float x2 = __shfl_xor(r2, 1), x3 = __shfl_xor(r3, 1);
    bool o1 = lane & 1;
    float s0 = o1 ? x1 : r0, s1 = o1 ? r1 : x0;
    float s2 = o1 ? x3 : r2, s3 = o1 ? r3 : x2;
    float y0 = __shfl_xor(s0, 2), y1 = __shfl_xor(s1, 2);
    float y2 = __shfl_xor(s2, 2), y3 = __shfl_xor(s3, 2);
    bool o2 = lane & 2;
    float gi = (o2 ? y2 : s0) + ai;
    float gf = (o2 ? y3 : s1) + af;
    float gg = (o2 ? s2 : y0) + ag;
    float go = (o2 ? s3 : y1) + ao;
    float I  = fast_sigmoid(gi);
    float Fg = fast_sigmoid(gf);
    float G  = fast_tanh(gg);
    float O  = fast_sigmoid(go);
    c = Fg * c + I * G;
    return O * fast_tanh(c);
}
__device__ inline void pack_plain(float h, int lane, u16* dst) {
    u32 hq = (u32)f2bf(h);
    u32 o4 = (u32)__shfl_xor((int)hq, 4);
    u32 m32 = (lane & 4) ? ((o4 & 0xffffu) | (hq << 16))
                         : ((hq & 0xffffu) | (o4 << 16));
    u32 o8 = (u32)__shfl_xor((int)m32, 8);
    u64 m64 = (lane & 8) ? (((u64)o8) | ((u64)m32 << 32))
                         : (((u64)m32) | ((u64)o8 << 32));
    if ((lane & 12) == 0) *(u64*)dst = m64;
}
__device__ inline int e0_of(int base) {
    return ((base & 15) >> 2) * 8 + ((base >> 4) & 1) * 4;
}

// ---------------- per-timestep kernel: boundary IS the sync (r15-proven) ----------
// 256 blocks x 256 threads (4 waves: mt=w&1 batch-half, qh=w>>1 K-half).
// blocks 0-127: L0 step t  (h0[t] in hbuf0 slot t&1 -> slot (t+1)&1), skip at t=512.
// blocks 128-255: L1 step t (h1[t-1] + h0[t]*Wx1 -> hseq1 slot t), skip at t=0.
// All loads/stores PLAIN (dependent-dispatch coherence). Weights frag-packed (k_wpackip):
// one 16B load per B-frag. c-state in f32 global, in-place per (b,unit) thread.
__launch_bounds__(256, 1)
__global__ void k_step(int t,
                       const u16* __restrict__ Wp0, const u16* __restrict__ Wpx,
                       const u16* __restrict__ Wp1, const u16* __restrict__ xproj,
                       const float* __restrict__ b1,
                       u16* __restrict__ hbuf0, u16* __restrict__ hseq1,
                       float* __restrict__ c0buf, float* __restrict__ c1buf) {
    __shared__ f32x4 part[2][2][2][64];   // [mt][ct][src H/X][lane]
    int tid = threadIdx.x, bid = blockIdx.x;
    int lane = tid & 63, w = tid >> 6;
    int mt = w & 1, qh = w >> 1;
    int rr = lane & 15, r16 = lane >> 4;
    int b_ = mt * 16 + ((lane >> 4) << 2) + (lane & 3);
    int uu = (lane >> 2) & 3;
    const int cb = mt * 512 + rr * 32 + r16 * 8;

    if (bid < 128) {
        if (t >= 512) return;
        int blk = bid;
        size_t cg0 = (size_t)((rr & 3) * 1024 + blk * 8 + (rr >> 2));
        const u16* w0 = Wp0 + cg0 * GK + qh * 512 + r16 * 8;
        const u16* w1 = Wp0 + (cg0 + 4) * GK + qh * 512 + r16 * 8;
        const u16* hp = hbuf0 + (size_t)(t & 1) * 32768 + qh * 16384 + cb;
        u32x4 hf[16];
#pragma unroll
        for (int j = 0; j < 16; ++j) hf[j] = *(const u32x4*)(hp + j * 1024);
        f32x4 a0 = {}, a1 = {};
#pragma unroll
        for (int j = 0; j < 16; ++j) {
            s16x8 a = __builtin_bit_cast(s16x8, hf[j]);
            a0 = mfma16(a, *(const s16x8*)(w0 + j * 32), a0);
            a1 = mfma16(a, *(const s16x8*)(w1 + j * 32), a1);
        }
        part[mt][1 - qh][0][lane] = qh ? a0 : a1;
        __syncthreads();
        f32x4 acc = (qh ? a1 : a0) + part[mt][qh][0][lane];
        int unit = blk * 8 + qh * 4 + uu;
        u64 xv = *(const u64*)(xproj + (size_t)(t * 32 + b_) * 4096 + unit * 4);
        float c = c0buf[b_ * 1024 + unit];
        float h = lstm_core(acc, h2f((u16)xv), h2f((u16)(xv >> 16)),
                            h2f((u16)(xv >> 32)), h2f((u16)(xv >> 48)), c, lane);
        c0buf[b_ * 1024 + unit] = c;
        int E0 = e0_of((blk & 3) * 8 + qh * 4);
        u16* dst = hbuf0 + (size_t)((t + 1) & 1) * 32768 + (blk >> 2) * 1024
                 + b_ * 32 + E0;
        pack_plain(h, lane, dst);
    } else {
        if (t < 1) return;
        int blk = bid - 128;
        size_t cg0 = (size_t)((rr & 3) * 1024 + blk * 8 + (rr >> 2));
        size_t woff = qh * 512 + r16 * 8;
        const u16* wh0 = Wp1 + cg0 * GK + woff;
        const u16* wh1 = Wp1 + (cg0 + 4) * GK + woff;
        const u16* wx0 = Wpx + cg0 * GK + woff;
        const u16* wx1 = Wpx + (cg0 + 4) * GK + woff;
        const u16* hp1 = hseq1 + (size_t)(t - 1) * 32768 + qh * 16384 + cb;
        const u16* hp0 = hbuf0 + (size_t)(t & 1) * 32768 + qh * 16384 + cb;
        u32x4 hf[16], gfr[16];
#pragma unroll
        for (int j = 0; j < 16; ++j) hf[j] = *(const u32x4*)(hp1 + j * 1024);
#pragma unroll
        for (int j = 0; j < 16; ++j) gfr[j] = *(const u32x4*)(hp0 + j * 1024);
        f32x4 aH0 = {}, aH1 = {}, aX0 = {}, aX1 = {};
#pragma unroll
        for (int j = 0; j < 16; ++j) {
            s16x8 a = __builtin_bit_cast(s16x8, hf[j]);
            aH0 = mfma16(a, *(const s16x8*)(wh0 + j * 32), aH0);
            aH1 = mfma16(a, *(const s16x8*)(wh1 + j * 32), aH1);
            s16x8 g = __builtin_bit_cast(s16x8, gfr[j]);
            aX0 = mfma16(g, *(const s16x8*)(wx0 + j * 32), aX0);
            aX1 = mfma16(g, *(const s16x8*)(wx1 + j * 32), aX1);
        }
        part[mt][1 - qh][0][lane] = qh ? aH0 : aH1;
        part[mt][1 - qh][1][lane] = qh ? aX0 : aX1;
        __syncthreads();
        f32x4 acc = (qh ? aH1 : aH0) + (qh ? aX1 : aX0)
                  + part[mt][qh][0][lane] + part[mt][qh][1][lane];
        int unit = blk * 8 + qh * 4 + uu;
        float c = c1buf[b_ * 1024 + unit];
        float h = lstm_core(acc, b1[unit], b1[1024 + unit], b1[2048 + unit],
                            b1[3072 + unit], c, lane);
        c1buf[b_ * 1024 + unit] = c;
        int E0 = e0_of((blk & 3) * 8 + qh * 4);
        u16* dst = hseq1 + (size_t)t * 32768 + (blk >> 2) * 1024 + b_ * 32 + E0;
        pack_plain(h, lane, dst);
    }
}

extern "C" void kernel_launch(void* const* d_in, const int* in_sizes, int n_in,
                              void* d_out, int out_size, void* d_ws, size_t ws_size,
                              hipStream_t stream) {
    const float* x   = (const float*)d_in[0];
    const float* Wx  = (const float*)d_in[1];
    const float* Wh  = (const float*)d_in[2];
    const float* b   = (const float*)d_in[3];
    const float* Wmu = (const float*)d_in[4];
    const float* bmu = (const float*)d_in[5];
    const float* Wls = (const float*)d_in[6];
    const float* bls = (const float*)d_in[7];
    const float* ym  = (const float*)d_in[8];
    float* out = (float*)d_out;

    // workspace (235,995,136 B total):
    // [0)            xbf (prep) -> then hbuf0[2][32768] (131,072) + c0 (131,072) + c1
    // [33,554,432)   wxT   16,777,216   [2][4096][1024]  (layer1 half frag-packed)
    // [50,331,648)   whT   16,777,216   (frag-packed in place)
    // [67,108,864)   whdT   1,048,576
    // [68,157,440)   xproj 134,217,728  fp16 gate-interleaved (h1lin alias after steps)
    // [202,375,168)  hseq1 33,619,968   [513][32768]
    char* ws = (char*)d_ws;
    u16*   xbf   = (u16*)(ws);
    u16*   hbuf0 = (u16*)(ws);                   // aliases xbf (dead after gemm0)
    float* c0buf = (float*)(ws + 131072);
    float* c1buf = (float*)(ws + 262144);
    u16*   wxT   = (u16*)(ws + 33554432);
    u16*   whT   = (u16*)(ws + 50331648);
    u16*   whdT  = (u16*)(ws + 67108864);
    u16*   xproj = (u16*)(ws + 68157440);
    u16*   h1lin = xproj;                        // xproj dead after steps
    u16*   hseq1 = (u16*)(ws + 202375168);

    // prep
    k_f2bf<<<16384, 256, 0, stream>>>(x, xbf, 16777216);
    dim3 tg(128, 32);
    k_transpose_bf<<<tg, 256, 0, stream>>>(Wx,           wxT,           1024, 4096);
    k_transpose_bf<<<tg, 256, 0, stream>>>(Wx + 4194304, wxT + 4194304, 1024, 4096);
    k_transpose_bf<<<tg, 256, 0, stream>>>(Wh,           whT,           1024, 4096);
    k_transpose_bf<<<tg, 256, 0, stream>>>(Wh + 4194304, whT + 4194304, 1024, 4096);
    dim3 hg(8, 32);
    k_transpose_bf<<<hg, 256, 0, stream>>>(Wmu, whdT,          1024, 256);
    k_transpose_bf<<<hg, 256, 0, stream>>>(Wls, whdT + 262144, 1024, 256);

    // layer-0 x-projection (reads xbf with UNPACKED wxT[0])
    k_gemm<0><<<4096, 256, 0, stream>>>(xbf, wxT, b, xproj, nullptr, nullptr, nullptr, 32);

    // frag-pack recurrence weights in place (whT both layers, wxT layer 1)
    k_wpackip<<<1024, 256, 0, stream>>>(whT);
    k_wpackip<<<512, 256, 0, stream>>>(wxT + 4194304);

    // init state (xbf dead now): h0 slot0, h1 slot0, c0, c1 = 0
    hipMemsetAsync(hbuf0, 0, 65536, stream);
    hipMemsetAsync(c0buf, 0, 262144, stream);      // c0 + c1
    hipMemsetAsync(hseq1, 0, 65536, stream);

    // 513 per-step kernels; dependent-dispatch boundary = global sync
    for (int t = 0; t <= 512; ++t)
        k_step<<<256, 256, 0, stream>>>(t, whT, wxT + 4194304, whT + 4194304, xproj,
                                        b + 4096, hbuf0, hseq1, c0buf, c1buf);

    // unpack hseq1 -> plain rows, then heads
    k_unpack<<<8192, 256, 0, stream>>>(hseq1, h1lin);
    k_gemm<1><<<512, 256, 0, stream>>>(h1lin, whdT, bmu, nullptr, out, bls, ym, 4);
}